// Round 3
// baseline (763.432 us; speedup 1.0000x reference)
//
#include <hip/hip_runtime.h>
#include <cmath>

// Problem constants (from reference)
#define NVOC 100      // atom-type vocab
#define DIMN 200      // hidden dim
#define LDA  204      // padded LDS stride for [32][200] tiles (float4-aligned)
#define DPD  204      // DIM + NADD
#define LDM  36       // stride for 32x32 LDS matrices
#define NTOT 8192     // total atoms
// grid = 256 molecules (1 block/CU), block = 512 threads (8 waves/CU, 2/SIMD)

// NOTE: macro parameter must NOT be named `w` — it would capture the .w member.
#define FMA4(acc, s, wv) do { \
    (acc).x = fmaf((s),(wv).x,(acc).x); \
    (acc).y = fmaf((s),(wv).y,(acc).y); \
    (acc).z = fmaf((s),(wv).z,(acc).z); \
    (acc).w = fmaf((s),(wv).w,(acc).w); } while(0)

#define RELU4(v) do { \
    (v).x=fmaxf((v).x,0.f); (v).y=fmaxf((v).y,0.f); \
    (v).z=fmaxf((v).z,0.f); (v).w=fmaxf((v).w,0.f); } while(0)

// out[2 rows x 8 cols] = src[2x200] @ W[200x200] + bias, per-thread tile.
// acc[0..1] = row r0 cols n0..n0+7 ; acc[2..3] = row r0+1.
// src rows from LDS (broadcast across the half-wave); W streamed from global
// (L1/L2-resident: all 256 blocks read the same 160 KB/layer).
__device__ __forceinline__ void gemm_tile2(const float* src,
                                           const float* __restrict__ W,
                                           const float* __restrict__ bias,
                                           int r0, int n0, float4 acc[4])
{
    const float4 b0 = *(const float4*)&bias[n0];
    const float4 b1 = *(const float4*)&bias[n0 + 4];
    acc[0] = b0; acc[1] = b1; acc[2] = b0; acc[3] = b1;

    #pragma unroll 2
    for (int k = 0; k < DIMN; k += 4) {
        const float4 a0 = *(const float4*)&src[(r0+0)*LDA + k];
        const float4 a1 = *(const float4*)&src[(r0+1)*LDA + k];
        const float* Wk = W + k*DIMN + n0;
        float4 w0, w1;
        w0 = *(const float4*)(Wk);          w1 = *(const float4*)(Wk + 4);
        FMA4(acc[0],a0.x,w0); FMA4(acc[1],a0.x,w1);
        FMA4(acc[2],a1.x,w0); FMA4(acc[3],a1.x,w1);
        w0 = *(const float4*)(Wk + DIMN);   w1 = *(const float4*)(Wk + DIMN + 4);
        FMA4(acc[0],a0.y,w0); FMA4(acc[1],a0.y,w1);
        FMA4(acc[2],a1.y,w0); FMA4(acc[3],a1.y,w1);
        w0 = *(const float4*)(Wk + 2*DIMN); w1 = *(const float4*)(Wk + 2*DIMN + 4);
        FMA4(acc[0],a0.z,w0); FMA4(acc[1],a0.z,w1);
        FMA4(acc[2],a1.z,w0); FMA4(acc[3],a1.z,w1);
        w0 = *(const float4*)(Wk + 3*DIMN); w1 = *(const float4*)(Wk + 3*DIMN + 4);
        FMA4(acc[0],a0.w,w0); FMA4(acc[1],a0.w,w1);
        FMA4(acc[2],a1.w,w0); FMA4(acc[3],a1.w,w1);
    }
}

__global__ __launch_bounds__(512, 2)
void mgnn_kernel(const int*   __restrict__ atoms,
                 const float* __restrict__ dist,
                 const float* __restrict__ adducts,
                 const float* __restrict__ embed,
                 const float* __restrict__ gamma_tab,
                 const float* __restrict__ Waw,
                 const float* __restrict__ Wab,
                 const float* __restrict__ Wow,
                 const float* __restrict__ Wob,
                 const float* __restrict__ Wpw,
                 const float* __restrict__ Wpb,
                 const float* __restrict__ Wprw,
                 const float* __restrict__ Wprb,
                 float* __restrict__ out)
{
    __shared__ float bufA[32*LDA];   // av  (26112 B)
    __shared__ float bufB[32*LDA];   // hv  (26112 B)
    __shared__ float d2s [32*LDM];   // squared intra-mol distances (4608 B)
    __shared__ float Mts [32*LDM];   // M transposed: Mts[j][r] = M[r][j] (4608 B)
    __shared__ int   atom_s[32];
    // total static LDS ~= 61.5 KB

    const int mol  = blockIdx.x;
    const int t    = threadIdx.x;
    const int base = mol * 32;
    // GEMM thread layout: row-group = half-wave (32 lanes), 25 active lanes.
    const int rowg = t >> 5;          // 0..15
    const int cg   = t & 31;          // 0..31, active < 25
    const bool act = cg < 25;
    const int r0 = rowg * 2;
    const int n0 = cg * 8;

    // ---- init: atoms, intra-molecule d^2 block, av0 = embed[atoms] ----
    if (t < 32) atom_s[t] = atoms[base + t];
    {
        const int j  = t >> 4;            // 0..31
        const int c2 = (t & 15) * 2;      // 0,2,...,30
        const float2 dd = *(const float2*)&dist[(size_t)(base + j) * NTOT + base + c2];
        float2 q; q.x = dd.x*dd.x; q.y = dd.y*dd.y;
        *(float2*)&d2s[j*LDM + c2] = q;
    }
    for (int idx = t; idx < 32*50; idx += 512) {
        const int r  = idx / 50;
        const int c4 = (idx % 50) * 4;
        const int a  = atoms[base + r];
        *(float4*)&bufA[r*LDA + c4] = *(const float4*)&embed[a*DIMN + c4];
    }
    __syncthreads();

    // ---- 6 hidden layers: hv = relu(av@W+b); av = normalize(hv + M@hv) ----
    for (int l = 0; l < 6; ++l) {
        float4 acc[4];
        if (act) {
            gemm_tile2(bufA, Waw + l*DIMN*DIMN, Wab + l*DIMN, r0, n0, acc);
            #pragma unroll
            for (int i = 0; i < 4; ++i) RELU4(acc[i]);
            *(float4*)&bufB[(r0+0)*LDA + n0]     = acc[0];
            *(float4*)&bufB[(r0+0)*LDA + n0 + 4] = acc[1];
            *(float4*)&bufB[(r0+1)*LDA + n0]     = acc[2];
            *(float4*)&bufB[(r0+1)*LDA + n0 + 4] = acc[3];
        }
        {   // Mts[j][r] = exp(-g[j]*d2[r][j]) ; d2 symmetric so use d2[j][r]
            const int j  = t >> 4;
            const int rr = (t & 15) * 2;
            const float g = gamma_tab[l*NVOC + atom_s[j]];
            const float2 d = *(const float2*)&d2s[j*LDM + rr];
            float2 m; m.x = expf(-g*d.x); m.y = expf(-g*d.y);
            *(float2*)&Mts[j*LDM + rr] = m;
        }
        __syncthreads();

        float s0 = 0.f, s1 = 0.f;
        if (act) {
            // av_new = hv + M@hv (block-local 32x32 propagation)
            acc[0] = *(const float4*)&bufB[(r0+0)*LDA + n0];
            acc[1] = *(const float4*)&bufB[(r0+0)*LDA + n0 + 4];
            acc[2] = *(const float4*)&bufB[(r0+1)*LDA + n0];
            acc[3] = *(const float4*)&bufB[(r0+1)*LDA + n0 + 4];
            #pragma unroll 4
            for (int j = 0; j < 32; ++j) {
                const float2 m  = *(const float2*)&Mts[j*LDM + r0];
                const float4 h0 = *(const float4*)&bufB[j*LDA + n0];
                const float4 h1 = *(const float4*)&bufB[j*LDA + n0 + 4];
                FMA4(acc[0],m.x,h0); FMA4(acc[1],m.x,h1);
                FMA4(acc[2],m.y,h0); FMA4(acc[3],m.y,h1);
            }
            s0 = acc[0].x*acc[0].x;
            s0 = fmaf(acc[0].y,acc[0].y,s0); s0 = fmaf(acc[0].z,acc[0].z,s0);
            s0 = fmaf(acc[0].w,acc[0].w,s0); s0 = fmaf(acc[1].x,acc[1].x,s0);
            s0 = fmaf(acc[1].y,acc[1].y,s0); s0 = fmaf(acc[1].z,acc[1].z,s0);
            s0 = fmaf(acc[1].w,acc[1].w,s0);
            s1 = acc[2].x*acc[2].x;
            s1 = fmaf(acc[2].y,acc[2].y,s1); s1 = fmaf(acc[2].z,acc[2].z,s1);
            s1 = fmaf(acc[2].w,acc[2].w,s1); s1 = fmaf(acc[3].x,acc[3].x,s1);
            s1 = fmaf(acc[3].y,acc[3].y,s1); s1 = fmaf(acc[3].z,acc[3].z,s1);
            s1 = fmaf(acc[3].w,acc[3].w,s1);
        }
        // row-norm: butterfly across the 32-lane half-wave (no LDS, no barrier)
        #pragma unroll
        for (int m = 16; m >= 1; m >>= 1) {
            s0 += __shfl_xor(s0, m, 32);
            s1 += __shfl_xor(s1, m, 32);
        }
        if (act) {
            const float sc0 = 1.0f / fmaxf(sqrtf(s0), 1e-12f);
            const float sc1 = 1.0f / fmaxf(sqrtf(s1), 1e-12f);
            acc[0].x*=sc0; acc[0].y*=sc0; acc[0].z*=sc0; acc[0].w*=sc0;
            acc[1].x*=sc0; acc[1].y*=sc0; acc[1].z*=sc0; acc[1].w*=sc0;
            acc[2].x*=sc1; acc[2].y*=sc1; acc[2].z*=sc1; acc[2].w*=sc1;
            acc[3].x*=sc1; acc[3].y*=sc1; acc[3].z*=sc1; acc[3].w*=sc1;
            *(float4*)&bufA[(r0+0)*LDA + n0]     = acc[0];
            *(float4*)&bufA[(r0+0)*LDA + n0 + 4] = acc[1];
            *(float4*)&bufA[(r0+1)*LDA + n0]     = acc[2];
            *(float4*)&bufA[(r0+1)*LDA + n0 + 4] = acc[3];
        }
        __syncthreads();
    }

    // ---- 3 out layers: av = relu(av@W+b), ping-pong A<->B ----
    float* cur = bufA;
    float* nxt = bufB;
    for (int l = 0; l < 3; ++l) {
        float4 acc[4];
        if (act) {
            gemm_tile2(cur, Wow + l*DIMN*DIMN, Wob + l*DIMN, r0, n0, acc);
            #pragma unroll
            for (int i = 0; i < 4; ++i) RELU4(acc[i]);
            *(float4*)&nxt[(r0+0)*LDA + n0]     = acc[0];
            *(float4*)&nxt[(r0+0)*LDA + n0 + 4] = acc[1];
            *(float4*)&nxt[(r0+1)*LDA + n0]     = acc[2];
            *(float4*)&nxt[(r0+1)*LDA + n0 + 4] = acc[3];
        }
        __syncthreads();
        float* tp = cur; cur = nxt; nxt = tp;
    }
    // final per-atom features now in `cur`

    // ---- molecule sum + adduct concat (d2s space reused for mv buffers) ----
    float* mv0 = d2s;         // 204 floats
    float* mv1 = d2s + 512;   // 204 floats
    if (t < DIMN) {
        float s = 0.f;
        #pragma unroll 4
        for (int r = 0; r < 32; ++r) s += cur[r*LDA + t];
        mv0[t] = s;
    } else if (t < DPD) {
        mv0[t] = adducts[mol*4 + (t - 200)];
    }
    __syncthreads();

    // ---- 3 pred layers on [204] vector ----
    float* pc = mv0;
    float* pn = mv1;
    for (int l = 0; l < 3; ++l) {
        if (t < DPD) {
            float acc = Wpb[l*DPD + t];
            const float* Wl = Wpw + l*DPD*DPD;
            #pragma unroll 4
            for (int k = 0; k < DPD; ++k)
                acc = fmaf(pc[k], Wl[k*DPD + t], acc);   // pc[k] = LDS broadcast, Wl coalesced
            pn[t] = fmaxf(acc, 0.f);
        }
        __syncthreads();
        float* tp = pc; pc = pn; pn = tp;
    }

    // ---- final property head: out = mv @ W_prop + b ----
    if (t < DPD) Mts[t] = pc[t] * Wprw[t];
    __syncthreads();
    if (t == 0) {
        float s = Wprb[0];
        for (int k = 0; k < DPD; ++k) s += Mts[k];
        out[mol] = s;
    }
}

extern "C" void kernel_launch(void* const* d_in, const int* in_sizes, int n_in,
                              void* d_out, int out_size, void* d_ws, size_t ws_size,
                              hipStream_t stream) {
    const int*   atoms   = (const int*)  d_in[0];
    const float* dist    = (const float*)d_in[1];
    const float* adducts = (const float*)d_in[2];
    const float* embed   = (const float*)d_in[3];
    const float* gamma_t = (const float*)d_in[4];
    const float* Waw     = (const float*)d_in[5];
    const float* Wab     = (const float*)d_in[6];
    const float* Wow     = (const float*)d_in[7];
    const float* Wob     = (const float*)d_in[8];
    const float* Wpw     = (const float*)d_in[9];
    const float* Wpb     = (const float*)d_in[10];
    const float* Wprw    = (const float*)d_in[11];
    const float* Wprb    = (const float*)d_in[12];
    (void)in_sizes; (void)n_in; (void)d_ws; (void)ws_size; (void)out_size;

    mgnn_kernel<<<dim3(256), dim3(512), 0, stream>>>(
        atoms, dist, adducts, embed, gamma_t,
        Waw, Wab, Wow, Wob, Wpw, Wpb, Wprw, Wprb,
        (float*)d_out);
}

// Round 4
// 550.211 us; speedup vs baseline: 1.3875x; 1.3875x over previous
//
#include <hip/hip_runtime.h>
#include <cmath>

// Problem constants
#define NVOC 100
#define DIMN 200
#define LDA  256      // swizzled LDS stride for av/hv rows
#define DPD  204      // DIM + NADD
#define LDM  36       // stride for 32x32 LDS matrices
#define NTOT 8192
// grid = 256 molecules (1 block/CU), block = 512 threads (8 waves, 2/SIMD)
// Lane layout: w = t>>6 (wave, owns cols 32w..32w+31), c8 = lane&7 (col grp of 4),
// rq = lane>>3 (row quad: rows 4rq..4rq+3). One W-load serves 4 rows x 4 cols.

#define FMA4(acc, s, wv) do { \
    (acc).x = fmaf((s),(wv).x,(acc).x); \
    (acc).y = fmaf((s),(wv).y,(acc).y); \
    (acc).z = fmaf((s),(wv).z,(acc).z); \
    (acc).w = fmaf((s),(wv).w,(acc).w); } while(0)

#define RELU4(v) do { \
    (v).x=fmaxf((v).x,0.f); (v).y=fmaxf((v).y,0.f); \
    (v).z=fmaxf((v).z,0.f); (v).w=fmaxf((v).w,0.f); } while(0)

// XOR swizzle: col c (dword) of row r lives at r*LDA + (c ^ 4*(r>>2)).
// Within any b128 access the 8 distinct row-quads (or 8 col-groups) map to the
// 8 distinct bank-quads -> conflict-free with 8-way broadcast.
__device__ __forceinline__ int swz(int r, int c) {
    return (r << 8) + (c ^ (((r >> 2) & 7) << 2));
}

// acc[j] = row r0+j, cols n0..n0+3.  src = swizzled LDS [32][LDA].
// W streamed from global: one b128 per k per wave, 16 FMA4 per 4 loads.
__device__ __forceinline__ void gemm512(const float* src,
                                        const float* __restrict__ Wg,
                                        const float* __restrict__ bg,
                                        int r0, int n0w, int sw, float4 acc[4])
{
    const float4 b = *(const float4*)&bg[n0w];
    acc[0] = b; acc[1] = b; acc[2] = b; acc[3] = b;
    #pragma unroll 2
    for (int k0 = 0; k0 < DIMN; k0 += 4) {
        const int ks = k0 ^ sw;
        const float4 a0 = *(const float4*)&src[(r0+0)*LDA + ks];
        const float4 a1 = *(const float4*)&src[(r0+1)*LDA + ks];
        const float4 a2 = *(const float4*)&src[(r0+2)*LDA + ks];
        const float4 a3 = *(const float4*)&src[(r0+3)*LDA + ks];
        const float* Wk = Wg + k0*DIMN + n0w;
        const float4 w0 = *(const float4*)(Wk);
        const float4 w1 = *(const float4*)(Wk + DIMN);
        const float4 w2 = *(const float4*)(Wk + 2*DIMN);
        const float4 w3 = *(const float4*)(Wk + 3*DIMN);
        FMA4(acc[0],a0.x,w0); FMA4(acc[1],a1.x,w0); FMA4(acc[2],a2.x,w0); FMA4(acc[3],a3.x,w0);
        FMA4(acc[0],a0.y,w1); FMA4(acc[1],a1.y,w1); FMA4(acc[2],a2.y,w1); FMA4(acc[3],a3.y,w1);
        FMA4(acc[0],a0.z,w2); FMA4(acc[1],a1.z,w2); FMA4(acc[2],a2.z,w2); FMA4(acc[3],a3.z,w2);
        FMA4(acc[0],a0.w,w3); FMA4(acc[1],a1.w,w3); FMA4(acc[2],a2.w,w3); FMA4(acc[3],a3.w,w3);
    }
}

__global__ __launch_bounds__(512, 2)
void mgnn_kernel(const int*   __restrict__ atoms,
                 const float* __restrict__ dist,
                 const float* __restrict__ adducts,
                 const float* __restrict__ embed,
                 const float* __restrict__ gamma_tab,
                 const float* __restrict__ Waw,
                 const float* __restrict__ Wab,
                 const float* __restrict__ Wow,
                 const float* __restrict__ Wob,
                 const float* __restrict__ Wpw,
                 const float* __restrict__ Wpb,
                 const float* __restrict__ Wprw,
                 const float* __restrict__ Wprb,
                 float* __restrict__ out)
{
    __shared__ float  bufA[32*LDA];   // av / hv, swizzled (32 KB)
    __shared__ float  d2s [32*LDM];   // squared intra-mol distances (4.6 KB)
    __shared__ float  Mts [32*LDM];   // Mts[j][r] = M[r][j] (4.6 KB)
    __shared__ float4 part4[64];      // norm partials [wave][rq] (1 KB)
    __shared__ float  scale_s[32];
    __shared__ float  red8[8];
    __shared__ int    atom_s[32];
    // total ~43 KB

    const int mol  = blockIdx.x;
    const int t    = threadIdx.x;
    const int base = mol * 32;
    const int w    = t >> 6;          // wave 0..7
    const int lane = t & 63;
    const int c8   = lane & 7;        // col group
    const int rq   = lane >> 3;       // row quad 0..7
    const int r0   = rq * 4;
    const int n0   = w * 32 + c8 * 4; // 0..252
    const bool act = (n0 < DIMN);     // n0<=196 -> all 4 cols valid
    const int n0w  = act ? n0 : 196;  // clamp to stay in-bounds on W reads
    const int sw   = (rq & 7) << 2;   // row swizzle for this thread's rows

    // ---- init ----
    if (t < 32) atom_s[t] = atoms[base + t];
    {   // intra-molecule d^2 block
        const int j  = t >> 4;
        const int c2 = (t & 15) * 2;
        const float2 dd = *(const float2*)&dist[(size_t)(base + j) * NTOT + base + c2];
        float2 q; q.x = dd.x*dd.x; q.y = dd.y*dd.y;
        *(float2*)&d2s[j*LDM + c2] = q;
    }
    for (int idx = t; idx < 32*50; idx += 512) {   // av0 = embed[atoms]
        const int r  = idx / 50;
        const int c4 = (idx % 50) * 4;
        const int a  = atoms[base + r];
        *(float4*)&bufA[swz(r, c4)] = *(const float4*)&embed[a*DIMN + c4];
    }
    __syncthreads();

    // ---- 6 hidden layers ----
    for (int l = 0; l < 6; ++l) {
        float4 acc[4];
        gemm512(bufA, Waw + l*DIMN*DIMN, Wab + l*DIMN, r0, n0w, sw, acc);
        #pragma unroll
        for (int i = 0; i < 4; ++i) RELU4(acc[i]);

        __syncthreads();   // B1: all GEMM reads of bufA done
        if (act) {
            #pragma unroll
            for (int i = 0; i < 4; ++i)
                *(float4*)&bufA[swz(r0+i, n0)] = acc[i];   // hv in place
        }
        {   // Mts[j][r] = exp(-g[j]*d2[r][j]) (d2 symmetric)
            const int j  = t >> 4;
            const int rr = (t & 15) * 2;
            const float g = gamma_tab[l*NVOC + atom_s[j]];
            const float2 d = *(const float2*)&d2s[j*LDM + rr];
            Mts[j*LDM + rr]     = expf(-g*d.x);
            Mts[j*LDM + rr + 1] = expf(-g*d.y);
        }
        __syncthreads();   // B2: hv + Mts visible

        // av_new = hv + M@hv  (acc already holds this thread's relu'd hv tile)
        #pragma unroll 4
        for (int jj = 0; jj < 32; ++jj) {
            const float4 m4 = *(const float4*)&Mts[jj*LDM + r0];
            const float4 h4 = *(const float4*)&bufA[swz(jj, n0)];
            FMA4(acc[0], m4.x, h4);
            FMA4(acc[1], m4.y, h4);
            FMA4(acc[2], m4.z, h4);
            FMA4(acc[3], m4.w, h4);
        }
        // row sum-of-squares: per-thread 4 rows x 4 cols -> float4
        float4 p;
        p.x = acc[0].x*acc[0].x; p.x = fmaf(acc[0].y,acc[0].y,p.x);
        p.x = fmaf(acc[0].z,acc[0].z,p.x); p.x = fmaf(acc[0].w,acc[0].w,p.x);
        p.y = acc[1].x*acc[1].x; p.y = fmaf(acc[1].y,acc[1].y,p.y);
        p.y = fmaf(acc[1].z,acc[1].z,p.y); p.y = fmaf(acc[1].w,acc[1].w,p.y);
        p.z = acc[2].x*acc[2].x; p.z = fmaf(acc[2].y,acc[2].y,p.z);
        p.z = fmaf(acc[2].z,acc[2].z,p.z); p.z = fmaf(acc[2].w,acc[2].w,p.z);
        p.w = acc[3].x*acc[3].x; p.w = fmaf(acc[3].y,acc[3].y,p.w);
        p.w = fmaf(acc[3].z,acc[3].z,p.w); p.w = fmaf(acc[3].w,acc[3].w,p.w);
        if (!act) { p.x = p.y = p.z = p.w = 0.f; }
        // reduce over the 8 col-groups (lanes rq*8..rq*8+7)
        #pragma unroll
        for (int m = 1; m < 8; m <<= 1) {
            p.x += __shfl_xor(p.x, m);
            p.y += __shfl_xor(p.y, m);
            p.z += __shfl_xor(p.z, m);
            p.w += __shfl_xor(p.w, m);
        }
        if (c8 == 0) part4[w*8 + rq] = p;
        __syncthreads();   // B3
        if (t < 32) {
            const float* pf = (const float*)part4;
            const int rqq = t >> 2, cm = t & 3;
            float s = 0.f;
            #pragma unroll
            for (int ww = 0; ww < 8; ++ww) s += pf[((ww*8 + rqq) << 2) + cm];
            scale_s[t] = 1.0f / fmaxf(sqrtf(s), 1e-12f);
        }
        __syncthreads();   // B4
        {
            const float4 sc4 = *(const float4*)&scale_s[r0];
            acc[0].x*=sc4.x; acc[0].y*=sc4.x; acc[0].z*=sc4.x; acc[0].w*=sc4.x;
            acc[1].x*=sc4.y; acc[1].y*=sc4.y; acc[1].z*=sc4.y; acc[1].w*=sc4.y;
            acc[2].x*=sc4.z; acc[2].y*=sc4.z; acc[2].z*=sc4.z; acc[2].w*=sc4.z;
            acc[3].x*=sc4.w; acc[3].y*=sc4.w; acc[3].z*=sc4.w; acc[3].w*=sc4.w;
            if (act) {
                #pragma unroll
                for (int i = 0; i < 4; ++i)
                    *(float4*)&bufA[swz(r0+i, n0)] = acc[i];   // av in place
            }
        }
        __syncthreads();   // B5: av visible for next layer
    }

    // ---- 3 out layers: av = relu(av@W+b), in place ----
    for (int l = 0; l < 3; ++l) {
        float4 acc[4];
        gemm512(bufA, Wow + l*DIMN*DIMN, Wob + l*DIMN, r0, n0w, sw, acc);
        #pragma unroll
        for (int i = 0; i < 4; ++i) RELU4(acc[i]);
        __syncthreads();
        if (act) {
            #pragma unroll
            for (int i = 0; i < 4; ++i)
                *(float4*)&bufA[swz(r0+i, n0)] = acc[i];
        }
        __syncthreads();
    }

    // ---- molecule sum + adduct concat (d2s reused for mv buffers) ----
    float* mv0 = d2s;
    float* mv1 = d2s + 256;
    if (t < DIMN) {
        float s = 0.f;
        #pragma unroll 4
        for (int r = 0; r < 32; ++r)
            s += bufA[(r << 8) + (t ^ (((r >> 2) & 7) << 2))];
        mv0[t] = s;
    } else if (t < DPD) {
        mv0[t] = adducts[mol*4 + (t - 200)];
    }
    __syncthreads();

    // ---- 3 pred layers on [204] vector ----
    float* pc = mv0;
    float* pn = mv1;
    for (int l = 0; l < 3; ++l) {
        if (t < DPD) {
            float acc = Wpb[l*DPD + t];
            const float* Wl = Wpw + l*DPD*DPD;
            #pragma unroll 4
            for (int k = 0; k < DPD; ++k)
                acc = fmaf(pc[k], Wl[k*DPD + t], acc);
            pn[t] = fmaxf(acc, 0.f);
        }
        __syncthreads();
        float* tp = pc; pc = pn; pn = tp;
    }

    // ---- final property head ----
    float v = (t < DPD) ? pc[t] * Wprw[t] : 0.f;
    #pragma unroll
    for (int m = 1; m < 64; m <<= 1) v += __shfl_xor(v, m);
    if (lane == 0) red8[w] = v;
    __syncthreads();
    if (t == 0) {
        float s = Wprb[0];
        #pragma unroll
        for (int ww = 0; ww < 8; ++ww) s += red8[ww];
        out[mol] = s;
    }
}

extern "C" void kernel_launch(void* const* d_in, const int* in_sizes, int n_in,
                              void* d_out, int out_size, void* d_ws, size_t ws_size,
                              hipStream_t stream) {
    const int*   atoms   = (const int*)  d_in[0];
    const float* dist    = (const float*)d_in[1];
    const float* adducts = (const float*)d_in[2];
    const float* embed   = (const float*)d_in[3];
    const float* gamma_t = (const float*)d_in[4];
    const float* Waw     = (const float*)d_in[5];
    const float* Wab     = (const float*)d_in[6];
    const float* Wow     = (const float*)d_in[7];
    const float* Wob     = (const float*)d_in[8];
    const float* Wpw     = (const float*)d_in[9];
    const float* Wpb     = (const float*)d_in[10];
    const float* Wprw    = (const float*)d_in[11];
    const float* Wprb    = (const float*)d_in[12];
    (void)in_sizes; (void)n_in; (void)d_ws; (void)ws_size; (void)out_size;

    mgnn_kernel<<<dim3(256), dim3(512), 0, stream>>>(
        atoms, dist, adducts, embed, gamma_t,
        Waw, Wab, Wow, Wob, Wpw, Wpb, Wprw, Wprb,
        (float*)d_out);
}